// Round 9
// baseline (426.679 us; speedup 1.0000x reference)
//
#include <hip/hip_runtime.h>
#include <cstdint>
#include <math.h>

#define S_LEN 2048
#define BATCH 2
#define HID   2048
#define NHEAD 16
#define DHEAD 128

typedef _Float16 h8 __attribute__((ext_vector_type(8)));
typedef _Float16 h4 __attribute__((ext_vector_type(4)));
typedef float f32x4 __attribute__((ext_vector_type(4)));

// async global->LDS, 16B per lane; LDS dest = wave-uniform base + lane*16
__device__ __forceinline__ void gload16(const void* g, void* l) {
  __builtin_amdgcn_global_load_lds(
      (const __attribute__((address_space(1))) unsigned int*)g,
      (__attribute__((address_space(3))) unsigned int*)l, 16, 0, 0);
}

// ---------------------------------------------------------------------------
// gemm_128 (R12, proven): BM=128, BN=256, BK=64, 8 waves (2M x 4N), per-wave
// 64x64, 2 phases/K-tile. Granule-XOR swizzle; prefetch distance 2; vmcnt(6).
// R17 note: gemm_128/gemm_256(4ph)/gemm_256v2(2ph) ALL land at 135-138us,
// 36-37% per-block util (m97-plateau) -> schedule-family ceiling; QKV uses
// this one (best measured: 133us, 768 blocks = 3 exact rounds).
// ---------------------------------------------------------------------------
template <bool HAS_BIAS, bool OUT_HALF>
__global__ __launch_bounds__(512) void gemm_128(
    const _Float16* __restrict__ A, const _Float16* __restrict__ Bt,
    const float* __restrict__ bias, void* __restrict__ Cout, int M, int N,
    int K) {
  __shared__ _Float16 LA[2][8192];   // [dbuf][128 rows x 64]
  __shared__ _Float16 LB[2][16384];  // [dbuf][256 rows x 64]
  const int tid = (int)threadIdx.x;
  const int wave = tid >> 6, lane = tid & 63;
  const int ln = lane & 15, quad = lane >> 4;
  const int wm = wave >> 2, wn = wave & 3;  // 2 x 4 wave grid, wave=64x64
  const int bm = (int)blockIdx.y * 128, bn = (int)blockIdx.x * 256;
  const int NT = K >> 6;

  const int gc8 = ((lane & 7) ^ (lane >> 3)) * 8;
  const uint32_t oA0 =
      (uint32_t)(bm + wave * 8 + (lane >> 3)) * (uint32_t)K + (uint32_t)gc8;
  const uint32_t oA1 = oA0 + (uint32_t)(64 * K);
  const uint32_t oB00 =
      (uint32_t)(bn + wave * 16 + (lane >> 3)) * (uint32_t)K + (uint32_t)gc8;
  const uint32_t oB01 = oB00 + (uint32_t)(8 * K);
  const uint32_t oB10 = oB00 + (uint32_t)(128 * K);
  const uint32_t oB11 = oB10 + (uint32_t)(8 * K);

#define STAGE128(bb_, u_)                                                    \
  {                                                                          \
    gload16(A + (oA0 + (uint32_t)(u_)*64u), &LA[bb_][wave * 512]);           \
    gload16(A + (oA1 + (uint32_t)(u_)*64u), &LA[bb_][4096 + wave * 512]);    \
    gload16(Bt + (oB00 + (uint32_t)(u_)*64u), &LB[bb_][wave * 1024]);        \
    gload16(Bt + (oB01 + (uint32_t)(u_)*64u), &LB[bb_][wave * 1024 + 512]);  \
    gload16(Bt + (oB10 + (uint32_t)(u_)*64u), &LB[bb_][8192 + wave * 1024]); \
    gload16(Bt + (oB11 + (uint32_t)(u_)*64u),                                \
            &LB[bb_][8192 + wave * 1024 + 512]);                             \
  }

  const int arow = ln * 64;
  const int sc0 = ((quad ^ (ln & 7))) * 8;
  const int sc1 = (((4 + quad) ^ (ln & 7))) * 8;
  const int abase = wm * 4096;
  const int bbase = wn * 4096;

  f32x4 acc[4][4];
#pragma unroll
  for (int m = 0; m < 4; m++)
#pragma unroll
    for (int n = 0; n < 4; n++) acc[m][n] = (f32x4){0.f, 0.f, 0.f, 0.f};
  h8 aF[4][2], bF[4][2];

#define HQUAD(n0_)                                                           \
  _Pragma("unroll") for (int mm_ = 0; mm_ < 4; mm_++)                        \
      _Pragma("unroll") for (int nn_ = 0; nn_ < 2; nn_++) {                  \
    acc[mm_][(n0_) + nn_] = __builtin_amdgcn_mfma_f32_16x16x32_f16(          \
        aF[mm_][0], bF[(n0_) + nn_][0], acc[mm_][(n0_) + nn_], 0, 0, 0);     \
    acc[mm_][(n0_) + nn_] = __builtin_amdgcn_mfma_f32_16x16x32_f16(          \
        aF[mm_][1], bF[(n0_) + nn_][1], acc[mm_][(n0_) + nn_], 0, 0, 0);     \
  }

  STAGE128(0, 0)
  STAGE128(1, 1)
  asm volatile("s_waitcnt vmcnt(6)" ::: "memory");
  __builtin_amdgcn_s_barrier();

  for (int u = 0; u < NT; ++u) {
    const int bb = u & 1;

#pragma unroll
    for (int m = 0; m < 4; m++) {
      aF[m][0] = *(const h8*)&LA[bb][abase + m * 1024 + arow + sc0];
      aF[m][1] = *(const h8*)&LA[bb][abase + m * 1024 + arow + sc1];
    }
#pragma unroll
    for (int n = 0; n < 2; n++) {
      bF[n][0] = *(const h8*)&LB[bb][bbase + n * 1024 + arow + sc0];
      bF[n][1] = *(const h8*)&LB[bb][bbase + n * 1024 + arow + sc1];
    }
    __builtin_amdgcn_s_barrier();
    __builtin_amdgcn_s_setprio(1);
    HQUAD(0)
    __builtin_amdgcn_s_setprio(0);
    __builtin_amdgcn_s_barrier();

#pragma unroll
    for (int n = 2; n < 4; n++) {
      bF[n][0] = *(const h8*)&LB[bb][bbase + n * 1024 + arow + sc0];
      bF[n][1] = *(const h8*)&LB[bb][bbase + n * 1024 + arow + sc1];
    }
    if (u + 2 < NT) {
      STAGE128(bb, u + 2)
      asm volatile("s_waitcnt vmcnt(6)" ::: "memory");
    } else if (u + 1 < NT) {
      asm volatile("s_waitcnt vmcnt(0)" ::: "memory");
    }
    __builtin_amdgcn_s_barrier();
    __builtin_amdgcn_s_setprio(1);
    HQUAD(2)
    __builtin_amdgcn_s_setprio(0);
    __builtin_amdgcn_s_barrier();
  }
#undef HQUAD
#undef STAGE128

#pragma unroll
  for (int m = 0; m < 4; m++) {
#pragma unroll
    for (int r = 0; r < 4; r++) {
      const size_t row = (size_t)(bm + wm * 64 + m * 16 + quad * 4 + r);
#pragma unroll
      for (int n = 0; n < 4; n++) {
        const int col = bn + wn * 64 + n * 16 + ln;
        float v = acc[m][n][r];
        if (HAS_BIAS) v += bias[col];
        if (OUT_HALF)
          ((_Float16*)Cout)[row * N + col] = (_Float16)v;
        else
          ((float*)Cout)[row * N + col] = v;
      }
    }
  }
}

// ---------------------------------------------------------------------------
// transpose_cvt (R12): out[n][k] = (fp16) in[k][n]; float4 loads, h4 stores.
// ---------------------------------------------------------------------------
__global__ __launch_bounds__(256) void transpose_cvt(
    const float* __restrict__ in, _Float16* __restrict__ out, int K, int N) {
  __shared__ float t[64][65];
  const int bn = blockIdx.x * 64, bk = blockIdx.y * 64;
  const int tid = (int)threadIdx.x;
  {
    const int r0 = tid >> 4, c4 = (tid & 15) * 4;
#pragma unroll
    for (int i = 0; i < 4; i++) {
      const int r = r0 + 16 * i;
      float4 v = *(const float4*)&in[(size_t)(bk + r) * N + bn + c4];
      t[r][c4] = v.x;
      t[r][c4 + 1] = v.y;
      t[r][c4 + 2] = v.z;
      t[r][c4 + 3] = v.w;
    }
  }
  __syncthreads();
  {
    const int c0 = tid >> 4, r4 = (tid & 15) * 4;
#pragma unroll
    for (int i = 0; i < 4; i++) {
      const int c = c0 + 16 * i;
      h4 o = {(_Float16)t[r4][c], (_Float16)t[r4 + 1][c],
              (_Float16)t[r4 + 2][c], (_Float16)t[r4 + 3][c]};
      *(h4*)&out[(size_t)(bn + c) * K + bk + r4] = o;
    }
  }
}

__global__ __launch_bounds__(256) void cvt_fp16(const float* __restrict__ in,
                                                _Float16* __restrict__ out,
                                                int n4) {
  int i = blockIdx.x * blockDim.x + threadIdx.x;
  if (i < n4) {
    float4 v = ((const float4*)in)[i];
    h4 o = {(_Float16)v.x, (_Float16)v.y, (_Float16)v.z, (_Float16)v.w};
    *(h4*)&out[4 * (size_t)i] = o;
  }
}

// ---------------------------------------------------------------------------
// pack_mask (R15): bool mask -> packed u32 with causal baked; shift < 32.
// ---------------------------------------------------------------------------
__global__ __launch_bounds__(256) void pack_mask(
    const unsigned char* __restrict__ m, uint32_t* __restrict__ pm) {
  const int i = blockIdx.x * 256 + threadIdx.x;  // B*S*64 words
  const int w = i & 63, r = (i >> 6) & (S_LEN - 1), b = i >> 17;
  const uint32_t* src =
      (const uint32_t*)(m + ((size_t)b * S_LEN + r) * S_LEN + w * 32);
  uint32_t bits = 0;
#pragma unroll
  for (int k = 0; k < 8; k++) {
    const uint32_t v = src[k];
    bits |= ((v & 0x000000FFu) ? 1u : 0u) << (4 * k);
    bits |= ((v & 0x0000FF00u) ? 1u : 0u) << (4 * k + 1);
    bits |= ((v & 0x00FF0000u) ? 1u : 0u) << (4 * k + 2);
    bits |= ((v & 0xFF000000u) ? 1u : 0u) << (4 * k + 3);
  }
  const int c0 = w * 32;
  uint32_t caus;
  if (c0 > r) {
    caus = 0xFFFFFFFFu;
  } else if (r - c0 >= 31) {
    caus = 0u;
  } else {
    caus = ~((2u << (r - c0)) - 1u);
  }
  pm[i] = bits | caus;
}

// ---------------------------------------------------------------------------
// pack_kv (unchanged since R8).
// ---------------------------------------------------------------------------
__global__ __launch_bounds__(256) void pack_kv(
    const _Float16* __restrict__ mixed, _Float16* __restrict__ KP,
    _Float16* __restrict__ VP) {
  __shared__ _Float16 Tv[128 * 40];
  const int kt = blockIdx.x;
  const int z = blockIdx.y;  // b*NH + h
  const int kb = kt * 32;
  const int tid = threadIdx.x;
  const size_t RS = (size_t)BATCH * NHEAD * 384;
  const _Float16* base = mixed + (size_t)z * 384;

  {
    const int r = tid >> 3, d0 = (tid & 7) * 16;
    const _Float16* src = base + (size_t)(kb + r) * RS + 256 + d0;
    h8 v0 = *(const h8*)src;
    h8 v1 = *(const h8*)(src + 8);
#pragma unroll
    for (int e = 0; e < 8; e++) Tv[(d0 + e) * 40 + r] = v0[e];
#pragma unroll
    for (int e = 0; e < 8; e++) Tv[(d0 + 8 + e) * 40 + r] = v1[e];
  }
  __syncthreads();

  const size_t tb = ((size_t)z * 64 + kt) * 8 * 512;
#pragma unroll
  for (int c = 0; c < 2; c++) {
    const int idx = tid + 256 * c;  // 0..511
    const int i = idx >> 6, l = idx & 63;
    const int ln = l & 15, quad = l >> 4;
    {
      const int jn = i >> 2, kq = i & 3;
      h8 v = *(const h8*)(base + (size_t)(kb + 16 * jn + ln) * RS + 128 +
                          32 * kq + 8 * quad);
      *(h8*)&KP[tb + (size_t)i * 512 + l * 8] = v;
    }
    {
      h8 v = *(const h8*)&Tv[(16 * i + ln) * 40 + 8 * quad];
      *(h8*)&VP[tb + (size_t)i * 512 + l * 8] = v;
    }
  }
}

// ---------------------------------------------------------------------------
// R18 flash_attn_v10: 4 waves x 32 q-rows (QBLK 128, 256 thr) — raises
// MFMA/LDS-read intensity 0.94 -> 1.78.
// WHY (R17 post-mortem): v9 is LDS-pipe-bound: per wave per tile 16 MFMA vs
// 17 ds_read_b128 + 8 ds_write_b16 (~1900cy LDS vs ~620cy MFMA per
// block-tile). v10: each wave owns TWO 16-row groups, so every K-frag and
// V-frag LDS read feeds TWO MFMAs (32 MFMA / 18 reads). Per-block-tile LDS
// 1888 -> 1120 cy. STAGE = v8's proven 256-thread pattern; grid/XCD decode
// = v9 (512 blocks, 2/CU, big-first). LDS 43 KB; VGPR ~145 (o 64 + q 32).
// ---------------------------------------------------------------------------
__global__ __launch_bounds__(256) void flash_attn_v10(
    const _Float16* __restrict__ mixed, const _Float16* __restrict__ KP,
    const _Float16* __restrict__ VP, const uint32_t* __restrict__ pmask,
    _Float16* __restrict__ ctx) {
  const int bid = (int)blockIdx.x;
  const int x = bid & 7, s = bid >> 3;
  const int z = x * 4 + (s & 3);  // XCD x -> z-planes 4x..4x+3
  const int qt = 15 - (s >> 2);   // big blocks first
  const int h = z & (NHEAD - 1), b = z >> 4;
  const int qb = qt * 128;
  const int tid = threadIdx.x;
  const int wave = tid >> 6, lane = tid & 63;  // wave 0..3, owns 32 rows
  const int ln = lane & 15, quad = lane >> 4;

  __shared__ _Float16 Kbuf[2][8 * 512];  // 2 x 8 KB, frag-chunk layout
  __shared__ _Float16 Vbuf[2][8 * 512];  // 2 x 8 KB
  __shared__ _Float16 St[4][32 * 40];    // 10.2 KB, per-wave P [32][32]

  const size_t RS = (size_t)BATCH * NHEAD * 384;
  const _Float16* base = mixed + (size_t)z * 384;
  const uint32_t* pmb = pmask + (size_t)b * S_LEN * 64;
  const float scale = 0.08838834764831845f;  // 1/sqrt(128)

  // ---- Q fragments (2 row-groups) -> registers, scaled ----
  h8 qfrag[2][4];
#pragma unroll
  for (int p = 0; p < 2; p++) {
    const size_t row = (size_t)(qb + 32 * wave + 16 * p + ln);
#pragma unroll
    for (int kq = 0; kq < 4; kq++) {
      h8 v = *(const h8*)(base + row * RS + 32 * kq + 8 * quad);
#pragma unroll
      for (int j = 0; j < 8; j++) v[j] = (_Float16)((float)v[j] * scale);
      qfrag[p][kq] = v;
    }
  }

  f32x4 o[2][8];
#pragma unroll
  for (int p = 0; p < 2; p++)
#pragma unroll
    for (int nt = 0; nt < 8; nt++) o[p][nt] = (f32x4){0.f, 0.f, 0.f, 0.f};
  float lpart[2][4] = {{0.f, 0.f, 0.f, 0.f}, {0.f, 0.f, 0.f, 0.f}};

  const int ntiles = 4 * qt + 4;  // K-tiles of 32, cols < qb+128

  // stage tile kt: 4 waves stage 8 K-chunks + 8 V-chunks (ch = 2w+c),
  // each chunk 1 KB contiguous (64 lanes x 16 B). (v8's proven pattern)
  const size_t zt = (size_t)z * 64;
#define STAGE(kt_, buf_)                                                   \
  {                                                                        \
    const size_t tbk = (zt + (kt_)) * (8 * 512) + lane * 8;                \
    _Pragma("unroll") for (int c = 0; c < 2; c++) {                        \
      const int ch = 2 * wave + c;                                         \
      gload16(KP + tbk + ch * 512, &Kbuf[buf_][ch * 512]);                 \
      gload16(VP + tbk + ch * 512, &Vbuf[buf_][ch * 512]);                 \
    }                                                                      \
  }

  STAGE(0, 0)  // prologue

  // packed-mask base for rows qb + 32w + 4q (+16p + r handled below)
  const uint32_t* pmr = pmb + (size_t)(qb + 32 * wave + 4 * quad) * 64;

  for (int kt = 0; kt < ntiles; kt++) {
    const int cur = kt & 1;
    __syncthreads();  // drains this tile's async loads; frees other buffer

    if (kt + 1 < ntiles) STAGE(kt + 1, cur ^ 1)  // lands during compute

    uint32_t mw[2][4];
#pragma unroll
    for (int p = 0; p < 2; p++)
#pragma unroll
      for (int r = 0; r < 4; r++)
        mw[p][r] = pmr[(size_t)(16 * p + r) * 64 + kt];

    // ---- QK^T: each K-frag read feeds both row-groups ----
    f32x4 sp[2][2];
#pragma unroll
    for (int p = 0; p < 2; p++)
#pragma unroll
      for (int jn = 0; jn < 2; jn++) sp[p][jn] = (f32x4){0.f, 0.f, 0.f, 0.f};
#pragma unroll
    for (int kq = 0; kq < 4; kq++) {
#pragma unroll
      for (int jn = 0; jn < 2; jn++) {
        h8 bk = *(const h8*)&Kbuf[cur][(jn * 4 + kq) * 512 + lane * 8];
        sp[0][jn] = __builtin_amdgcn_mfma_f32_16x16x32_f16(qfrag[0][kq], bk,
                                                           sp[0][jn], 0, 0, 0);
        sp[1][jn] = __builtin_amdgcn_mfma_f32_16x16x32_f16(qfrag[1][kq], bk,
                                                           sp[1][jn], 0, 0, 0);
      }
    }

    // ---- no-max softmax -> wave-private St [32][32] ----
#pragma unroll
    for (int p = 0; p < 2; p++)
#pragma unroll
      for (int r = 0; r < 4; r++) {
        const uint32_t ms = mw[p][r] >> ln;  // bit 16*jn = col kb+16jn+ln
#pragma unroll
        for (int jn = 0; jn < 2; jn++) {
          const float sv =
              ((ms >> (16 * jn)) & 1u) ? -10000.0f : sp[p][jn][r];
          const float pe = __expf(sv);
          lpart[p][r] += pe;
          St[wave][(16 * p + 4 * quad + r) * 40 + 16 * jn + ln] =
              (_Float16)pe;
        }
      }
    __threadfence_block();

    // ---- PV: each V-frag read feeds both row-groups ----
    {
      h8 ap0 = *(const h8*)&St[wave][ln * 40 + 8 * quad];
      h8 ap1 = *(const h8*)&St[wave][(16 + ln) * 40 + 8 * quad];
#pragma unroll
      for (int nt = 0; nt < 8; nt++) {
        h8 bv = *(const h8*)&Vbuf[cur][nt * 512 + lane * 8];
        o[0][nt] =
            __builtin_amdgcn_mfma_f32_16x16x32_f16(ap0, bv, o[0][nt], 0, 0, 0);
        o[1][nt] =
            __builtin_amdgcn_mfma_f32_16x16x32_f16(ap1, bv, o[1][nt], 0, 0, 0);
      }
    }
  }
#undef STAGE

  // ---- epilogue: l reduction, normalize, write fp16 ctx ----
#pragma unroll
  for (int p = 0; p < 2; p++)
#pragma unroll
    for (int r = 0; r < 4; r++) {
      float l = lpart[p][r];
#pragma unroll
      for (int off = 8; off >= 1; off >>= 1) l += __shfl_xor(l, off, 16);
      const float inv_l = 1.0f / l;
      const size_t row_g = (size_t)(qb + 32 * wave + 16 * p + 4 * quad + r);
      _Float16* dst = ctx + (row_g * BATCH + b) * HID + h * DHEAD;
#pragma unroll
      for (int nt = 0; nt < 8; nt++)
        dst[16 * nt + ln] = (_Float16)(o[p][nt][r] * inv_l);
    }
}

__global__ void copy_bias(const float* __restrict__ src,
                          float* __restrict__ dst) {
  int i = blockIdx.x * blockDim.x + threadIdx.x;
  if (i < HID) dst[i] = src[i];
}

extern "C" void kernel_launch(void* const* d_in, const int* in_sizes, int n_in,
                              void* d_out, int out_size, void* d_ws,
                              size_t ws_size, hipStream_t stream) {
  (void)in_sizes;
  (void)n_in;
  const float* hs = (const float*)d_in[0];
  const unsigned char* mask = (const unsigned char*)d_in[1];
  const float* qkv_w = (const float*)d_in[2];
  const float* qkv_b = (const float*)d_in[3];
  const float* proj_w = (const float*)d_in[4];
  const float* proj_b = (const float*)d_in[5];
  float* out = (float*)d_out;

  const size_t M = (size_t)S_LEN * BATCH;
  const size_t mixed_e = M * 3 * HID;            // 25.17M halves
  const size_t qkvwt_e = (size_t)3 * HID * HID;  // 12.58M (>= VP 8.39M)
  const size_t hsh_e = M * HID;                  // 8.39M (== KP 8.39M)
  const size_t projwt_e = (size_t)HID * HID;     // 4.19M
  const size_t ctx_e = M * HID;                  // 8.39M
  const size_t need =
      (mixed_e + qkvwt_e + hsh_e + projwt_e + ctx_e) * sizeof(_Float16);
  if (ws_size < need) return;  // 117.5 MB, proven available

  _Float16* mixed = (_Float16*)d_ws;
  _Float16* qkv_wt = mixed + mixed_e;   // aliased as VP after QKV GEMM
  _Float16* hs_h = qkv_wt + qkvwt_e;    // aliased as KP after QKV GEMM
  _Float16* proj_wt = hs_h + hsh_e;
  _Float16* ctx = proj_wt + projwt_e;
  _Float16* KP = hs_h;
  _Float16* VP = qkv_wt;
  // packed mask (1 MB) scratched into d_out: dead until proj GEMM, fully
  // overwritten by it afterwards.
  uint32_t* pmask = (uint32_t*)out;

  cvt_fp16<<<(int)(hsh_e / 4 / 256), 256, 0, stream>>>(hs, hs_h,
                                                       (int)(hsh_e / 4));
  transpose_cvt<<<dim3(3 * HID / 64, HID / 64), 256, 0, stream>>>(
      qkv_w, qkv_wt, HID, 3 * HID);
  transpose_cvt<<<dim3(HID / 64, HID / 64), 256, 0, stream>>>(
      proj_w, proj_wt, HID, HID);
  pack_mask<<<(BATCH * S_LEN * 64) / 256, 256, 0, stream>>>(mask, pmask);

  // QKV: grid (6144/256) x (4096/128) = 24 x 32 = 768 blocks = 3 full rounds
  gemm_128<true, true><<<dim3(3 * HID / 256, M / 128), 512, 0, stream>>>(
      hs_h, qkv_wt, qkv_b, mixed, (int)M, 3 * HID, HID);

  pack_kv<<<dim3(S_LEN / 32, BATCH * NHEAD), 256, 0, stream>>>(mixed, KP, VP);

  // flash v10: 1D grid, 512 blocks (16 qt x 32 z), 256 thr, XCD decode
  flash_attn_v10<<<512, 256, 0, stream>>>(mixed, KP, VP, pmask, ctx);

  // proj: grid (2048/256) x (4096/128) = 256 blocks = 1 full round
  gemm_128<false, false><<<dim3(HID / 256, M / 128), 512, 0, stream>>>(
      ctx, proj_wt, nullptr, out, (int)M, HID, HID);

  copy_bias<<<(HID + 255) / 256, 256, 0, stream>>>(proj_b, out + M * HID);
}

// Round 10
// 414.180 us; speedup vs baseline: 1.0302x; 1.0302x over previous
//
#include <hip/hip_runtime.h>
#include <cstdint>
#include <math.h>

#define S_LEN 2048
#define BATCH 2
#define HID   2048
#define NHEAD 16
#define DHEAD 128

typedef _Float16 h8 __attribute__((ext_vector_type(8)));
typedef _Float16 h4 __attribute__((ext_vector_type(4)));
typedef float f32x4 __attribute__((ext_vector_type(4)));

// async global->LDS, 16B per lane; LDS dest = wave-uniform base + lane*16
__device__ __forceinline__ void gload16(const void* g, void* l) {
  __builtin_amdgcn_global_load_lds(
      (const __attribute__((address_space(1))) unsigned int*)g,
      (__attribute__((address_space(3))) unsigned int*)l, 16, 0, 0);
}

// ---------------------------------------------------------------------------
// gemm_256v2 (R16, verified): 256x256 tile, 8 waves (2M x 4N), per-wave
// 128x64, BK=64, 2 phases/K-tile. Best per-block throughput measured:
// 68.8us/block = 997 TF-equiv (48% per-block MFMA). R19: used where its
// grid is an EXACT round (QKV cols [0,4096): 16x16 = 256 blocks).
// ---------------------------------------------------------------------------
template <bool HAS_BIAS, bool OUT_HALF>
__global__ __launch_bounds__(512) void gemm_256v2(
    const _Float16* __restrict__ A, const _Float16* __restrict__ Bt,
    const float* __restrict__ bias, void* __restrict__ Cout, int M, int N,
    int K) {
  __shared__ _Float16 LA[2][16384];  // [dbuf][256 rows x 64]
  __shared__ _Float16 LB[2][16384];  // [dbuf][256 rows x 64]
  const int tid = (int)threadIdx.x;
  const int wave = tid >> 6, lane = tid & 63;
  const int ln = lane & 15, quad = lane >> 4;
  const int wm = wave >> 2, wn = wave & 3;  // 2 x 4 wave grid, wave=128x64
  const int bm = (int)blockIdx.y * 256, bn = (int)blockIdx.x * 256;
  const int NT = K >> 6;

  const int gc8 = ((lane & 7) ^ (lane >> 3)) * 8;
  const int rbase = wave * 8 + (lane >> 3);
  uint32_t oA[4], oB[4];
#pragma unroll
  for (int q = 0; q < 4; q++) {
    oA[q] = (uint32_t)(bm + q * 64 + rbase) * (uint32_t)K + (uint32_t)gc8;
    oB[q] = (uint32_t)(bn + q * 64 + rbase) * (uint32_t)K + (uint32_t)gc8;
  }

#define STAGEA(bb_, u_)                                                  \
  {                                                                      \
    _Pragma("unroll") for (int q = 0; q < 4; q++)                        \
        gload16(A + (oA[q] + (uint32_t)(u_)*64u),                        \
                &LA[bb_][q * 4096 + wave * 512]);                        \
  }
#define STAGEB(bb_, u_)                                                  \
  {                                                                      \
    _Pragma("unroll") for (int q = 0; q < 4; q++)                        \
        gload16(Bt + (oB[q] + (uint32_t)(u_)*64u),                       \
                &LB[bb_][q * 4096 + wave * 512]);                        \
  }

  const int arow = ln * 64;
  const int sc0 = ((quad ^ (ln & 7))) * 8;
  const int sc1 = (((4 + quad) ^ (ln & 7))) * 8;
  const int abase = wm * 8192;  // wave's 128 A-rows
  const int bbase = wn * 4096;  // wave's 64 B-rows

  f32x4 acc[8][4];
#pragma unroll
  for (int m = 0; m < 8; m++)
#pragma unroll
    for (int n = 0; n < 4; n++) acc[m][n] = (f32x4){0.f, 0.f, 0.f, 0.f};
  h8 aF[4][2], bF[4][2];

#define HALF(mo_)                                                            \
  _Pragma("unroll") for (int mm_ = 0; mm_ < 4; mm_++)                        \
      _Pragma("unroll") for (int nn_ = 0; nn_ < 4; nn_++) {                  \
    acc[(mo_) + mm_][nn_] = __builtin_amdgcn_mfma_f32_16x16x32_f16(          \
        aF[mm_][0], bF[nn_][0], acc[(mo_) + mm_][nn_], 0, 0, 0);             \
    acc[(mo_) + mm_][nn_] = __builtin_amdgcn_mfma_f32_16x16x32_f16(          \
        aF[mm_][1], bF[nn_][1], acc[(mo_) + mm_][nn_], 0, 0, 0);             \
  }

  STAGEA(0, 0) STAGEB(0, 0)
  STAGEA(1, 1) STAGEB(1, 1)
  asm volatile("s_waitcnt vmcnt(8)" ::: "memory");
  __builtin_amdgcn_s_barrier();

  for (int u = 0; u < NT; ++u) {
    const int bb = u & 1;

#pragma unroll
    for (int m = 0; m < 4; m++) {
      aF[m][0] = *(const h8*)&LA[bb][abase + m * 1024 + arow + sc0];
      aF[m][1] = *(const h8*)&LA[bb][abase + m * 1024 + arow + sc1];
    }
#pragma unroll
    for (int n = 0; n < 4; n++) {
      bF[n][0] = *(const h8*)&LB[bb][bbase + n * 1024 + arow + sc0];
      bF[n][1] = *(const h8*)&LB[bb][bbase + n * 1024 + arow + sc1];
    }
    __builtin_amdgcn_s_barrier();
    __builtin_amdgcn_s_setprio(1);
    HALF(0)
    __builtin_amdgcn_s_setprio(0);
    __builtin_amdgcn_s_barrier();

#pragma unroll
    for (int m = 0; m < 4; m++) {
      aF[m][0] = *(const h8*)&LA[bb][abase + (m + 4) * 1024 + arow + sc0];
      aF[m][1] = *(const h8*)&LA[bb][abase + (m + 4) * 1024 + arow + sc1];
    }
    if (u + 2 < NT) {
      STAGEA(bb, u + 2) STAGEB(bb, u + 2)
      asm volatile("s_waitcnt vmcnt(8)" ::: "memory");
    } else if (u + 1 < NT) {
      asm volatile("s_waitcnt vmcnt(0)" ::: "memory");
    }
    __builtin_amdgcn_s_barrier();
    __builtin_amdgcn_s_setprio(1);
    HALF(4)
    __builtin_amdgcn_s_setprio(0);
    __builtin_amdgcn_s_barrier();
  }
#undef HALF
#undef STAGEA
#undef STAGEB

#pragma unroll
  for (int m = 0; m < 8; m++) {
#pragma unroll
    for (int r = 0; r < 4; r++) {
      const size_t row = (size_t)(bm + wm * 128 + m * 16 + quad * 4 + r);
#pragma unroll
      for (int n = 0; n < 4; n++) {
        const int col = bn + wn * 64 + n * 16 + ln;
        float v = acc[m][n][r];
        if (HAS_BIAS) v += bias[col];
        if (OUT_HALF)
          ((_Float16*)Cout)[row * N + col] = (_Float16)v;
        else
          ((float*)Cout)[row * N + col] = v;
      }
    }
  }
}

// ---------------------------------------------------------------------------
// gemm_128 (R12, proven): BM=128, BN=256, BK=64, 8 waves, per-wave 64x64,
// 2 phases/K-tile. 44.3us/block = 775 TF-equiv. Used where ITS grid is an
// exact round: QKV cols [4096,6144) (8x32=256) and proj (8x32=256).
// ---------------------------------------------------------------------------
template <bool HAS_BIAS, bool OUT_HALF>
__global__ __launch_bounds__(512) void gemm_128(
    const _Float16* __restrict__ A, const _Float16* __restrict__ Bt,
    const float* __restrict__ bias, void* __restrict__ Cout, int M, int N,
    int K) {
  __shared__ _Float16 LA[2][8192];   // [dbuf][128 rows x 64]
  __shared__ _Float16 LB[2][16384];  // [dbuf][256 rows x 64]
  const int tid = (int)threadIdx.x;
  const int wave = tid >> 6, lane = tid & 63;
  const int ln = lane & 15, quad = lane >> 4;
  const int wm = wave >> 2, wn = wave & 3;  // 2 x 4 wave grid, wave=64x64
  const int bm = (int)blockIdx.y * 128, bn = (int)blockIdx.x * 256;
  const int NT = K >> 6;

  const int gc8 = ((lane & 7) ^ (lane >> 3)) * 8;
  const uint32_t oA0 =
      (uint32_t)(bm + wave * 8 + (lane >> 3)) * (uint32_t)K + (uint32_t)gc8;
  const uint32_t oA1 = oA0 + (uint32_t)(64 * K);
  const uint32_t oB00 =
      (uint32_t)(bn + wave * 16 + (lane >> 3)) * (uint32_t)K + (uint32_t)gc8;
  const uint32_t oB01 = oB00 + (uint32_t)(8 * K);
  const uint32_t oB10 = oB00 + (uint32_t)(128 * K);
  const uint32_t oB11 = oB10 + (uint32_t)(8 * K);

#define STAGE128(bb_, u_)                                                    \
  {                                                                          \
    gload16(A + (oA0 + (uint32_t)(u_)*64u), &LA[bb_][wave * 512]);           \
    gload16(A + (oA1 + (uint32_t)(u_)*64u), &LA[bb_][4096 + wave * 512]);    \
    gload16(Bt + (oB00 + (uint32_t)(u_)*64u), &LB[bb_][wave * 1024]);        \
    gload16(Bt + (oB01 + (uint32_t)(u_)*64u), &LB[bb_][wave * 1024 + 512]);  \
    gload16(Bt + (oB10 + (uint32_t)(u_)*64u), &LB[bb_][8192 + wave * 1024]); \
    gload16(Bt + (oB11 + (uint32_t)(u_)*64u),                                \
            &LB[bb_][8192 + wave * 1024 + 512]);                             \
  }

  const int arow = ln * 64;
  const int sc0 = ((quad ^ (ln & 7))) * 8;
  const int sc1 = (((4 + quad) ^ (ln & 7))) * 8;
  const int abase = wm * 4096;
  const int bbase = wn * 4096;

  f32x4 acc[4][4];
#pragma unroll
  for (int m = 0; m < 4; m++)
#pragma unroll
    for (int n = 0; n < 4; n++) acc[m][n] = (f32x4){0.f, 0.f, 0.f, 0.f};
  h8 aF[4][2], bF[4][2];

#define HQUAD(n0_)                                                           \
  _Pragma("unroll") for (int mm_ = 0; mm_ < 4; mm_++)                        \
      _Pragma("unroll") for (int nn_ = 0; nn_ < 2; nn_++) {                  \
    acc[mm_][(n0_) + nn_] = __builtin_amdgcn_mfma_f32_16x16x32_f16(          \
        aF[mm_][0], bF[(n0_) + nn_][0], acc[mm_][(n0_) + nn_], 0, 0, 0);     \
    acc[mm_][(n0_) + nn_] = __builtin_amdgcn_mfma_f32_16x16x32_f16(          \
        aF[mm_][1], bF[(n0_) + nn_][1], acc[mm_][(n0_) + nn_], 0, 0, 0);     \
  }

  STAGE128(0, 0)
  STAGE128(1, 1)
  asm volatile("s_waitcnt vmcnt(6)" ::: "memory");
  __builtin_amdgcn_s_barrier();

  for (int u = 0; u < NT; ++u) {
    const int bb = u & 1;

#pragma unroll
    for (int m = 0; m < 4; m++) {
      aF[m][0] = *(const h8*)&LA[bb][abase + m * 1024 + arow + sc0];
      aF[m][1] = *(const h8*)&LA[bb][abase + m * 1024 + arow + sc1];
    }
#pragma unroll
    for (int n = 0; n < 2; n++) {
      bF[n][0] = *(const h8*)&LB[bb][bbase + n * 1024 + arow + sc0];
      bF[n][1] = *(const h8*)&LB[bb][bbase + n * 1024 + arow + sc1];
    }
    __builtin_amdgcn_s_barrier();
    __builtin_amdgcn_s_setprio(1);
    HQUAD(0)
    __builtin_amdgcn_s_setprio(0);
    __builtin_amdgcn_s_barrier();

#pragma unroll
    for (int n = 2; n < 4; n++) {
      bF[n][0] = *(const h8*)&LB[bb][bbase + n * 1024 + arow + sc0];
      bF[n][1] = *(const h8*)&LB[bb][bbase + n * 1024 + arow + sc1];
    }
    if (u + 2 < NT) {
      STAGE128(bb, u + 2)
      asm volatile("s_waitcnt vmcnt(6)" ::: "memory");
    } else if (u + 1 < NT) {
      asm volatile("s_waitcnt vmcnt(0)" ::: "memory");
    }
    __builtin_amdgcn_s_barrier();
    __builtin_amdgcn_s_setprio(1);
    HQUAD(2)
    __builtin_amdgcn_s_setprio(0);
    __builtin_amdgcn_s_barrier();
  }
#undef HQUAD
#undef STAGE128

#pragma unroll
  for (int m = 0; m < 4; m++) {
#pragma unroll
    for (int r = 0; r < 4; r++) {
      const size_t row = (size_t)(bm + wm * 64 + m * 16 + quad * 4 + r);
#pragma unroll
      for (int n = 0; n < 4; n++) {
        const int col = bn + wn * 64 + n * 16 + ln;
        float v = acc[m][n][r];
        if (HAS_BIAS) v += bias[col];
        if (OUT_HALF)
          ((_Float16*)Cout)[row * N + col] = (_Float16)v;
        else
          ((float*)Cout)[row * N + col] = v;
      }
    }
  }
}

// ---------------------------------------------------------------------------
// transpose_cvt (R12): out[n][k] = (fp16) in[k][n]; float4 loads, h4 stores.
// ---------------------------------------------------------------------------
__global__ __launch_bounds__(256) void transpose_cvt(
    const float* __restrict__ in, _Float16* __restrict__ out, int K, int N) {
  __shared__ float t[64][65];
  const int bn = blockIdx.x * 64, bk = blockIdx.y * 64;
  const int tid = (int)threadIdx.x;
  {
    const int r0 = tid >> 4, c4 = (tid & 15) * 4;
#pragma unroll
    for (int i = 0; i < 4; i++) {
      const int r = r0 + 16 * i;
      float4 v = *(const float4*)&in[(size_t)(bk + r) * N + bn + c4];
      t[r][c4] = v.x;
      t[r][c4 + 1] = v.y;
      t[r][c4 + 2] = v.z;
      t[r][c4 + 3] = v.w;
    }
  }
  __syncthreads();
  {
    const int c0 = tid >> 4, r4 = (tid & 15) * 4;
#pragma unroll
    for (int i = 0; i < 4; i++) {
      const int c = c0 + 16 * i;
      h4 o = {(_Float16)t[r4][c], (_Float16)t[r4 + 1][c],
              (_Float16)t[r4 + 2][c], (_Float16)t[r4 + 3][c]};
      *(h4*)&out[(size_t)(bn + c) * K + bk + r4] = o;
    }
  }
}

__global__ __launch_bounds__(256) void cvt_fp16(const float* __restrict__ in,
                                                _Float16* __restrict__ out,
                                                int n4) {
  int i = blockIdx.x * blockDim.x + threadIdx.x;
  if (i < n4) {
    float4 v = ((const float4*)in)[i];
    h4 o = {(_Float16)v.x, (_Float16)v.y, (_Float16)v.z, (_Float16)v.w};
    *(h4*)&out[4 * (size_t)i] = o;
  }
}

// ---------------------------------------------------------------------------
// pack_mask (R15): bool mask -> packed u32 with causal baked; shift < 32.
// ---------------------------------------------------------------------------
__global__ __launch_bounds__(256) void pack_mask(
    const unsigned char* __restrict__ m, uint32_t* __restrict__ pm) {
  const int i = blockIdx.x * 256 + threadIdx.x;  // B*S*64 words
  const int w = i & 63, r = (i >> 6) & (S_LEN - 1), b = i >> 17;
  const uint32_t* src =
      (const uint32_t*)(m + ((size_t)b * S_LEN + r) * S_LEN + w * 32);
  uint32_t bits = 0;
#pragma unroll
  for (int k = 0; k < 8; k++) {
    const uint32_t v = src[k];
    bits |= ((v & 0x000000FFu) ? 1u : 0u) << (4 * k);
    bits |= ((v & 0x0000FF00u) ? 1u : 0u) << (4 * k + 1);
    bits |= ((v & 0x00FF0000u) ? 1u : 0u) << (4 * k + 2);
    bits |= ((v & 0xFF000000u) ? 1u : 0u) << (4 * k + 3);
  }
  const int c0 = w * 32;
  uint32_t caus;
  if (c0 > r) {
    caus = 0xFFFFFFFFu;
  } else if (r - c0 >= 31) {
    caus = 0u;
  } else {
    caus = ~((2u << (r - c0)) - 1u);
  }
  pm[i] = bits | caus;
}

// ---------------------------------------------------------------------------
// pack_kv (unchanged since R8).
// ---------------------------------------------------------------------------
__global__ __launch_bounds__(256) void pack_kv(
    const _Float16* __restrict__ mixed, _Float16* __restrict__ KP,
    _Float16* __restrict__ VP) {
  __shared__ _Float16 Tv[128 * 40];
  const int kt = blockIdx.x;
  const int z = blockIdx.y;  // b*NH + h
  const int kb = kt * 32;
  const int tid = threadIdx.x;
  const size_t RS = (size_t)BATCH * NHEAD * 384;
  const _Float16* base = mixed + (size_t)z * 384;

  {
    const int r = tid >> 3, d0 = (tid & 7) * 16;
    const _Float16* src = base + (size_t)(kb + r) * RS + 256 + d0;
    h8 v0 = *(const h8*)src;
    h8 v1 = *(const h8*)(src + 8);
#pragma unroll
    for (int e = 0; e < 8; e++) Tv[(d0 + e) * 40 + r] = v0[e];
#pragma unroll
    for (int e = 0; e < 8; e++) Tv[(d0 + 8 + e) * 40 + r] = v1[e];
  }
  __syncthreads();

  const size_t tb = ((size_t)z * 64 + kt) * 8 * 512;
#pragma unroll
  for (int c = 0; c < 2; c++) {
    const int idx = tid + 256 * c;  // 0..511
    const int i = idx >> 6, l = idx & 63;
    const int ln = l & 15, quad = l >> 4;
    {
      const int jn = i >> 2, kq = i & 3;
      h8 v = *(const h8*)(base + (size_t)(kb + 16 * jn + ln) * RS + 128 +
                          32 * kq + 8 * quad);
      *(h8*)&KP[tb + (size_t)i * 512 + l * 8] = v;
    }
    {
      h8 v = *(const h8*)&Tv[(16 * i + ln) * 40 + 8 * quad];
      *(h8*)&VP[tb + (size_t)i * 512 + l * 8] = v;
    }
  }
}

// ---------------------------------------------------------------------------
// flash_attn_v9 (R17, best measured; REVERTED from v10 which halved
// waves/CU 16->8 and regressed): QBLK 128, 8 waves x 16 q-rows, 512 thr;
// XCD-aware 1D grid (XCD x owns z-planes 4x..4x+3, qt descending).
// ---------------------------------------------------------------------------
__global__ __launch_bounds__(512) void flash_attn_v9(
    const _Float16* __restrict__ mixed, const _Float16* __restrict__ KP,
    const _Float16* __restrict__ VP, const uint32_t* __restrict__ pmask,
    _Float16* __restrict__ ctx) {
  const int bid = (int)blockIdx.x;
  const int x = bid & 7, s = bid >> 3;
  const int z = x * 4 + (s & 3);        // XCD x -> z-planes 4x..4x+3
  const int qt = 15 - (s >> 2);         // big blocks first
  const int h = z & (NHEAD - 1), b = z >> 4;
  const int qb = qt * 128;
  const int tid = threadIdx.x;
  const int wave = tid >> 6, lane = tid & 63;
  const int ln = lane & 15, quad = lane >> 4;

  __shared__ _Float16 Kbuf[2][8 * 512];  // 2 x 8 KB, frag-chunk layout
  __shared__ _Float16 Vbuf[2][8 * 512];  // 2 x 8 KB
  __shared__ _Float16 St[8][16 * 40];    // 10.2 KB, per-wave P [16][32]

  const size_t RS = (size_t)BATCH * NHEAD * 384;
  const _Float16* base = mixed + (size_t)z * 384;
  const uint32_t* pmb = pmask + (size_t)b * S_LEN * 64;
  const float scale = 0.08838834764831845f;  // 1/sqrt(128)

  h8 qfrag[4];
  {
    const size_t row = (size_t)(qb + 16 * wave + ln);
#pragma unroll
    for (int kq = 0; kq < 4; kq++) {
      h8 v = *(const h8*)(base + row * RS + 32 * kq + 8 * quad);
#pragma unroll
      for (int j = 0; j < 8; j++) v[j] = (_Float16)((float)v[j] * scale);
      qfrag[kq] = v;
    }
  }

  f32x4 o[8];
#pragma unroll
  for (int nt = 0; nt < 8; nt++) o[nt] = (f32x4){0.f, 0.f, 0.f, 0.f};
  float lpart[4] = {0.f, 0.f, 0.f, 0.f};

  const int ntiles = 4 * qt + 4;  // K-tiles of 32, covering rows < qb+128

  const size_t zt = (size_t)z * 64;
#define STAGE(kt_, buf_)                                            \
  {                                                                 \
    const size_t tbk = (zt + (kt_)) * (8 * 512) + lane * 8;         \
    gload16(KP + tbk + wave * 512, &Kbuf[buf_][wave * 512]);        \
    gload16(VP + tbk + wave * 512, &Vbuf[buf_][wave * 512]);        \
  }

  STAGE(0, 0)  // prologue

  const uint32_t* pmr = pmb + (size_t)(qb + 16 * wave + 4 * quad) * 64;

  for (int kt = 0; kt < ntiles; kt++) {
    const int cur = kt & 1;
    __syncthreads();  // drains this tile's async loads; frees other buffer

    if (kt + 1 < ntiles) STAGE(kt + 1, cur ^ 1)  // lands during compute

    uint32_t mw[4];
#pragma unroll
    for (int r = 0; r < 4; r++) mw[r] = pmr[(size_t)r * 64 + kt];

    f32x4 sreg[2];
    sreg[0] = (f32x4){0.f, 0.f, 0.f, 0.f};
    sreg[1] = (f32x4){0.f, 0.f, 0.f, 0.f};
#pragma unroll
    for (int kq = 0; kq < 4; kq++) {
#pragma unroll
      for (int jn = 0; jn < 2; jn++) {
        h8 bk = *(const h8*)&Kbuf[cur][(jn * 4 + kq) * 512 + lane * 8];
        sreg[jn] = __builtin_amdgcn_mfma_f32_16x16x32_f16(qfrag[kq], bk,
                                                          sreg[jn], 0, 0, 0);
      }
    }

#pragma unroll
    for (int r = 0; r < 4; r++) {
      const uint32_t ms = mw[r] >> ln;  // bit 16*jn for col kb+16jn+ln
#pragma unroll
      for (int jn = 0; jn < 2; jn++) {
        const float sv =
            ((ms >> (16 * jn)) & 1u) ? -10000.0f : sreg[jn][r];
        const float p = __expf(sv);
        lpart[r] += p;
        St[wave][(4 * quad + r) * 40 + 16 * jn + ln] = (_Float16)p;
      }
    }
    __threadfence_block();

    {
      h8 ap = *(const h8*)&St[wave][ln * 40 + 8 * quad];
#pragma unroll
      for (int nt = 0; nt < 8; nt++) {
        h8 bv = *(const h8*)&Vbuf[cur][nt * 512 + lane * 8];
        o[nt] = __builtin_amdgcn_mfma_f32_16x16x32_f16(ap, bv, o[nt], 0, 0, 0);
      }
    }
  }
#undef STAGE

#pragma unroll
  for (int r = 0; r < 4; r++) {
    float l = lpart[r];
#pragma unroll
    for (int off = 8; off >= 1; off >>= 1) l += __shfl_xor(l, off, 16);
    const float inv_l = 1.0f / l;
    const size_t row_g = (size_t)(qb + 16 * wave + 4 * quad + r);
    _Float16* dst = ctx + (row_g * BATCH + b) * HID + h * DHEAD;
#pragma unroll
    for (int nt = 0; nt < 8; nt++)
      dst[16 * nt + ln] = (_Float16)(o[nt][r] * inv_l);
  }
}

__global__ void copy_bias(const float* __restrict__ src,
                          float* __restrict__ dst) {
  int i = blockIdx.x * blockDim.x + threadIdx.x;
  if (i < HID) dst[i] = src[i];
}

extern "C" void kernel_launch(void* const* d_in, const int* in_sizes, int n_in,
                              void* d_out, int out_size, void* d_ws,
                              size_t ws_size, hipStream_t stream) {
  (void)in_sizes;
  (void)n_in;
  const float* hs = (const float*)d_in[0];
  const unsigned char* mask = (const unsigned char*)d_in[1];
  const float* qkv_w = (const float*)d_in[2];
  const float* qkv_b = (const float*)d_in[3];
  const float* proj_w = (const float*)d_in[4];
  const float* proj_b = (const float*)d_in[5];
  float* out = (float*)d_out;

  const size_t M = (size_t)S_LEN * BATCH;
  const size_t mixed_e = M * 3 * HID;            // 25.17M halves
  const size_t qkvwt_e = (size_t)3 * HID * HID;  // 12.58M (>= VP 8.39M)
  const size_t hsh_e = M * HID;                  // 8.39M (== KP 8.39M)
  const size_t projwt_e = (size_t)HID * HID;     // 4.19M
  const size_t ctx_e = M * HID;                  // 8.39M
  const size_t need =
      (mixed_e + qkvwt_e + hsh_e + projwt_e + ctx_e) * sizeof(_Float16);
  if (ws_size < need) return;  // 117.5 MB, proven available

  _Float16* mixed = (_Float16*)d_ws;
  _Float16* qkv_wt = mixed + mixed_e;   // aliased as VP after QKV GEMM
  _Float16* hs_h = qkv_wt + qkvwt_e;    // aliased as KP after QKV GEMM
  _Float16* proj_wt = hs_h + hsh_e;
  _Float16* ctx = proj_wt + projwt_e;
  _Float16* KP = hs_h;
  _Float16* VP = qkv_wt;
  // packed mask (1 MB) scratched into d_out: dead until proj GEMM, fully
  // overwritten by it afterwards.
  uint32_t* pmask = (uint32_t*)out;

  cvt_fp16<<<(int)(hsh_e / 4 / 256), 256, 0, stream>>>(hs, hs_h,
                                                       (int)(hsh_e / 4));
  transpose_cvt<<<dim3(3 * HID / 64, HID / 64), 256, 0, stream>>>(
      qkv_w, qkv_wt, HID, 3 * HID);
  transpose_cvt<<<dim3(HID / 64, HID / 64), 256, 0, stream>>>(
      proj_w, proj_wt, HID, HID);
  pack_mask<<<(BATCH * S_LEN * 64) / 256, 256, 0, stream>>>(mask, pmask);

  // QKV split into two EXACT-one-round dispatches (R19):
  //   cols [0,4096):    gemm_256v2, grid 16x16 = 256 blocks (997 TF/block)
  //   cols [4096,6144): gemm_128,   grid 8x32  = 256 blocks (775 TF/block)
  // Pointer-shift only: Bt + 4096*K rows, bias + 4096, Cout + 4096 cols
  // (row stride N=6144 passed unchanged).
  gemm_256v2<true, true><<<dim3(16, (int)(M / 256)), 512, 0, stream>>>(
      hs_h, qkv_wt, qkv_b, mixed, (int)M, 3 * HID, HID);
  gemm_128<true, true><<<dim3(8, (int)(M / 128)), 512, 0, stream>>>(
      hs_h, qkv_wt + (size_t)4096 * HID, qkv_b + 4096,
      (void*)(mixed + 4096), (int)M, 3 * HID, HID);

  pack_kv<<<dim3(S_LEN / 32, BATCH * NHEAD), 256, 0, stream>>>(mixed, KP, VP);

  // flash v9: 1D grid, 512 blocks (16 qt x 32 z), XCD-aware decode inside
  flash_attn_v9<<<512, 512, 0, stream>>>(mixed, KP, VP, pmask, ctx);

  // proj: gemm_128 grid (2048/256) x (4096/128) = 256 blocks = 1 full round
  gemm_128<false, false><<<dim3(HID / 256, M / 128), 512, 0, stream>>>(
      ctx, proj_wt, nullptr, out, (int)M, HID, HID);

  copy_bias<<<(HID + 255) / 256, 256, 0, stream>>>(proj_b, out + M * HID);
}

// Round 12
// 404.087 us; speedup vs baseline: 1.0559x; 1.0250x over previous
//
#include <hip/hip_runtime.h>
#include <cstdint>
#include <math.h>

#define S_LEN 2048
#define BATCH 2
#define HID   2048
#define NHEAD 16
#define DHEAD 128

typedef _Float16 h8 __attribute__((ext_vector_type(8)));
typedef _Float16 h4 __attribute__((ext_vector_type(4)));
typedef float f32x4 __attribute__((ext_vector_type(4)));

// async global->LDS, 16B per lane; LDS dest = wave-uniform base + lane*16
__device__ __forceinline__ void gload16(const void* g, void* l) {
  __builtin_amdgcn_global_load_lds(
      (const __attribute__((address_space(1))) unsigned int*)g,
      (__attribute__((address_space(3))) unsigned int*)l, 16, 0, 0);
}

// ---------------------------------------------------------------------------
// gemm_256v2 (R16, verified): 256x256 tile, 8 waves (2M x 4N), per-wave
// 128x64, BK=64, 2 phases/K-tile. 997 TF-equiv/block. QKV cols [0,4096):
// grid 16x16 = 256 blocks = 1 exact round.
// ---------------------------------------------------------------------------
template <bool HAS_BIAS, bool OUT_HALF>
__global__ __launch_bounds__(512) void gemm_256v2(
    const _Float16* __restrict__ A, const _Float16* __restrict__ Bt,
    const float* __restrict__ bias, void* __restrict__ Cout, int M, int N,
    int K) {
  __shared__ _Float16 LA[2][16384];  // [dbuf][256 rows x 64]
  __shared__ _Float16 LB[2][16384];  // [dbuf][256 rows x 64]
  const int tid = (int)threadIdx.x;
  const int wave = tid >> 6, lane = tid & 63;
  const int ln = lane & 15, quad = lane >> 4;
  const int wm = wave >> 2, wn = wave & 3;  // 2 x 4 wave grid, wave=128x64
  const int bm = (int)blockIdx.y * 256, bn = (int)blockIdx.x * 256;
  const int NT = K >> 6;

  const int gc8 = ((lane & 7) ^ (lane >> 3)) * 8;
  const int rbase = wave * 8 + (lane >> 3);
  uint32_t oA[4], oB[4];
#pragma unroll
  for (int q = 0; q < 4; q++) {
    oA[q] = (uint32_t)(bm + q * 64 + rbase) * (uint32_t)K + (uint32_t)gc8;
    oB[q] = (uint32_t)(bn + q * 64 + rbase) * (uint32_t)K + (uint32_t)gc8;
  }

#define STAGEA(bb_, u_)                                                  \
  {                                                                      \
    _Pragma("unroll") for (int q = 0; q < 4; q++)                        \
        gload16(A + (oA[q] + (uint32_t)(u_)*64u),                        \
                &LA[bb_][q * 4096 + wave * 512]);                        \
  }
#define STAGEB(bb_, u_)                                                  \
  {                                                                      \
    _Pragma("unroll") for (int q = 0; q < 4; q++)                        \
        gload16(Bt + (oB[q] + (uint32_t)(u_)*64u),                       \
                &LB[bb_][q * 4096 + wave * 512]);                        \
  }

  const int arow = ln * 64;
  const int sc0 = ((quad ^ (ln & 7))) * 8;
  const int sc1 = (((4 + quad) ^ (ln & 7))) * 8;
  const int abase = wm * 8192;  // wave's 128 A-rows
  const int bbase = wn * 4096;  // wave's 64 B-rows

  f32x4 acc[8][4];
#pragma unroll
  for (int m = 0; m < 8; m++)
#pragma unroll
    for (int n = 0; n < 4; n++) acc[m][n] = (f32x4){0.f, 0.f, 0.f, 0.f};
  h8 aF[4][2], bF[4][2];

#define HALF(mo_)                                                            \
  _Pragma("unroll") for (int mm_ = 0; mm_ < 4; mm_++)                        \
      _Pragma("unroll") for (int nn_ = 0; nn_ < 4; nn_++) {                  \
    acc[(mo_) + mm_][nn_] = __builtin_amdgcn_mfma_f32_16x16x32_f16(          \
        aF[mm_][0], bF[nn_][0], acc[(mo_) + mm_][nn_], 0, 0, 0);             \
    acc[(mo_) + mm_][nn_] = __builtin_amdgcn_mfma_f32_16x16x32_f16(          \
        aF[mm_][1], bF[nn_][1], acc[(mo_) + mm_][nn_], 0, 0, 0);             \
  }

  STAGEA(0, 0) STAGEB(0, 0)
  STAGEA(1, 1) STAGEB(1, 1)
  asm volatile("s_waitcnt vmcnt(8)" ::: "memory");
  __builtin_amdgcn_s_barrier();

  for (int u = 0; u < NT; ++u) {
    const int bb = u & 1;

#pragma unroll
    for (int m = 0; m < 4; m++) {
      aF[m][0] = *(const h8*)&LA[bb][abase + m * 1024 + arow + sc0];
      aF[m][1] = *(const h8*)&LA[bb][abase + m * 1024 + arow + sc1];
    }
#pragma unroll
    for (int n = 0; n < 4; n++) {
      bF[n][0] = *(const h8*)&LB[bb][bbase + n * 1024 + arow + sc0];
      bF[n][1] = *(const h8*)&LB[bb][bbase + n * 1024 + arow + sc1];
    }
    __builtin_amdgcn_s_barrier();
    __builtin_amdgcn_s_setprio(1);
    HALF(0)
    __builtin_amdgcn_s_setprio(0);
    __builtin_amdgcn_s_barrier();

#pragma unroll
    for (int m = 0; m < 4; m++) {
      aF[m][0] = *(const h8*)&LA[bb][abase + (m + 4) * 1024 + arow + sc0];
      aF[m][1] = *(const h8*)&LA[bb][abase + (m + 4) * 1024 + arow + sc1];
    }
    if (u + 2 < NT) {
      STAGEA(bb, u + 2) STAGEB(bb, u + 2)
      asm volatile("s_waitcnt vmcnt(8)" ::: "memory");
    } else if (u + 1 < NT) {
      asm volatile("s_waitcnt vmcnt(0)" ::: "memory");
    }
    __builtin_amdgcn_s_barrier();
    __builtin_amdgcn_s_setprio(1);
    HALF(4)
    __builtin_amdgcn_s_setprio(0);
    __builtin_amdgcn_s_barrier();
  }
#undef HALF
#undef STAGEA
#undef STAGEB

#pragma unroll
  for (int m = 0; m < 8; m++) {
#pragma unroll
    for (int r = 0; r < 4; r++) {
      const size_t row = (size_t)(bm + wm * 128 + m * 16 + quad * 4 + r);
#pragma unroll
      for (int n = 0; n < 4; n++) {
        const int col = bn + wn * 64 + n * 16 + ln;
        float v = acc[m][n][r];
        if (HAS_BIAS) v += bias[col];
        if (OUT_HALF)
          ((_Float16*)Cout)[row * N + col] = (_Float16)v;
        else
          ((float*)Cout)[row * N + col] = v;
      }
    }
  }
}

// ---------------------------------------------------------------------------
// gemm_128 (R12, proven): BM=128, BN=256, BK=64, 775 TF-equiv/block. Used
// where its grid is an exact round: QKV cols [4096,6144) and proj (both 256).
// ---------------------------------------------------------------------------
template <bool HAS_BIAS, bool OUT_HALF>
__global__ __launch_bounds__(512) void gemm_128(
    const _Float16* __restrict__ A, const _Float16* __restrict__ Bt,
    const float* __restrict__ bias, void* __restrict__ Cout, int M, int N,
    int K) {
  __shared__ _Float16 LA[2][8192];   // [dbuf][128 rows x 64]
  __shared__ _Float16 LB[2][16384];  // [dbuf][256 rows x 64]
  const int tid = (int)threadIdx.x;
  const int wave = tid >> 6, lane = tid & 63;
  const int ln = lane & 15, quad = lane >> 4;
  const int wm = wave >> 2, wn = wave & 3;  // 2 x 4 wave grid, wave=64x64
  const int bm = (int)blockIdx.y * 128, bn = (int)blockIdx.x * 256;
  const int NT = K >> 6;

  const int gc8 = ((lane & 7) ^ (lane >> 3)) * 8;
  const uint32_t oA0 =
      (uint32_t)(bm + wave * 8 + (lane >> 3)) * (uint32_t)K + (uint32_t)gc8;
  const uint32_t oA1 = oA0 + (uint32_t)(64 * K);
  const uint32_t oB00 =
      (uint32_t)(bn + wave * 16 + (lane >> 3)) * (uint32_t)K + (uint32_t)gc8;
  const uint32_t oB01 = oB00 + (uint32_t)(8 * K);
  const uint32_t oB10 = oB00 + (uint32_t)(128 * K);
  const uint32_t oB11 = oB10 + (uint32_t)(8 * K);

#define STAGE128(bb_, u_)                                                    \
  {                                                                          \
    gload16(A + (oA0 + (uint32_t)(u_)*64u), &LA[bb_][wave * 512]);           \
    gload16(A + (oA1 + (uint32_t)(u_)*64u), &LA[bb_][4096 + wave * 512]);    \
    gload16(Bt + (oB00 + (uint32_t)(u_)*64u), &LB[bb_][wave * 1024]);        \
    gload16(Bt + (oB01 + (uint32_t)(u_)*64u), &LB[bb_][wave * 1024 + 512]);  \
    gload16(Bt + (oB10 + (uint32_t)(u_)*64u), &LB[bb_][8192 + wave * 1024]); \
    gload16(Bt + (oB11 + (uint32_t)(u_)*64u),                                \
            &LB[bb_][8192 + wave * 1024 + 512]);                             \
  }

  const int arow = ln * 64;
  const int sc0 = ((quad ^ (ln & 7))) * 8;
  const int sc1 = (((4 + quad) ^ (ln & 7))) * 8;
  const int abase = wm * 4096;
  const int bbase = wn * 4096;

  f32x4 acc[4][4];
#pragma unroll
  for (int m = 0; m < 4; m++)
#pragma unroll
    for (int n = 0; n < 4; n++) acc[m][n] = (f32x4){0.f, 0.f, 0.f, 0.f};
  h8 aF[4][2], bF[4][2];

#define HQUAD(n0_)                                                           \
  _Pragma("unroll") for (int mm_ = 0; mm_ < 4; mm_++)                        \
      _Pragma("unroll") for (int nn_ = 0; nn_ < 2; nn_++) {                  \
    acc[mm_][(n0_) + nn_] = __builtin_amdgcn_mfma_f32_16x16x32_f16(          \
        aF[mm_][0], bF[(n0_) + nn_][0], acc[mm_][(n0_) + nn_], 0, 0, 0);     \
    acc[mm_][(n0_) + nn_] = __builtin_amdgcn_mfma_f32_16x16x32_f16(          \
        aF[mm_][1], bF[(n0_) + nn_][1], acc[mm_][(n0_) + nn_], 0, 0, 0);     \
  }

  STAGE128(0, 0)
  STAGE128(1, 1)
  asm volatile("s_waitcnt vmcnt(6)" ::: "memory");
  __builtin_amdgcn_s_barrier();

  for (int u = 0; u < NT; ++u) {
    const int bb = u & 1;

#pragma unroll
    for (int m = 0; m < 4; m++) {
      aF[m][0] = *(const h8*)&LA[bb][abase + m * 1024 + arow + sc0];
      aF[m][1] = *(const h8*)&LA[bb][abase + m * 1024 + arow + sc1];
    }
#pragma unroll
    for (int n = 0; n < 2; n++) {
      bF[n][0] = *(const h8*)&LB[bb][bbase + n * 1024 + arow + sc0];
      bF[n][1] = *(const h8*)&LB[bb][bbase + n * 1024 + arow + sc1];
    }
    __builtin_amdgcn_s_barrier();
    __builtin_amdgcn_s_setprio(1);
    HQUAD(0)
    __builtin_amdgcn_s_setprio(0);
    __builtin_amdgcn_s_barrier();

#pragma unroll
    for (int n = 2; n < 4; n++) {
      bF[n][0] = *(const h8*)&LB[bb][bbase + n * 1024 + arow + sc0];
      bF[n][1] = *(const h8*)&LB[bb][bbase + n * 1024 + arow + sc1];
    }
    if (u + 2 < NT) {
      STAGE128(bb, u + 2)
      asm volatile("s_waitcnt vmcnt(6)" ::: "memory");
    } else if (u + 1 < NT) {
      asm volatile("s_waitcnt vmcnt(0)" ::: "memory");
    }
    __builtin_amdgcn_s_barrier();
    __builtin_amdgcn_s_setprio(1);
    HQUAD(2)
    __builtin_amdgcn_s_setprio(0);
    __builtin_amdgcn_s_barrier();
  }
#undef HQUAD
#undef STAGE128

#pragma unroll
  for (int m = 0; m < 4; m++) {
#pragma unroll
    for (int r = 0; r < 4; r++) {
      const size_t row = (size_t)(bm + wm * 64 + m * 16 + quad * 4 + r);
#pragma unroll
      for (int n = 0; n < 4; n++) {
        const int col = bn + wn * 64 + n * 16 + ln;
        float v = acc[m][n][r];
        if (HAS_BIAS) v += bias[col];
        if (OUT_HALF)
          ((_Float16*)Cout)[row * N + col] = (_Float16)v;
        else
          ((float*)Cout)[row * N + col] = v;
      }
    }
  }
}

// ---------------------------------------------------------------------------
// prep (R20, resubmitted R21 after infra failure): fused cvt_fp16 +
// transpose(qkv_w) + transpose(proj_w) + pack_mask + copy_bias. One launch
// instead of five. All branch ranges block-uniform; 256 thr.
//   [0,8192):        cvt_fp16 (hs -> hs_h, 2,097,152 float4s)
//   [8192,11264):    transpose qkv_w (96 x 32 tiles)
//   [11264,12288):   transpose proj_w (32 x 32 tiles)
//   [12288,13312):   pack_mask (262,144 words)
//   [13312,13320):   copy_bias (2048 floats, bound-checked)
// ---------------------------------------------------------------------------
__device__ __forceinline__ void transpose_body(const float* in, _Float16* out,
                                               int K, int N, int bx, int by,
                                               int tid, float (*t)[65]) {
  const int bn = bx * 64, bk = by * 64;
  {
    const int r0 = tid >> 4, c4 = (tid & 15) * 4;
#pragma unroll
    for (int i = 0; i < 4; i++) {
      const int r = r0 + 16 * i;
      float4 v = *(const float4*)&in[(size_t)(bk + r) * N + bn + c4];
      t[r][c4] = v.x;
      t[r][c4 + 1] = v.y;
      t[r][c4 + 2] = v.z;
      t[r][c4 + 3] = v.w;
    }
  }
  __syncthreads();
  {
    const int c0 = tid >> 4, r4 = (tid & 15) * 4;
#pragma unroll
    for (int i = 0; i < 4; i++) {
      const int c = c0 + 16 * i;
      h4 o = {(_Float16)t[r4][c], (_Float16)t[r4 + 1][c],
              (_Float16)t[r4 + 2][c], (_Float16)t[r4 + 3][c]};
      *(h4*)&out[(size_t)(bn + c) * K + bk + r4] = o;
    }
  }
}

__global__ __launch_bounds__(256) void prep(
    const float* __restrict__ hs, _Float16* __restrict__ hs_h,
    const float* __restrict__ qkv_w, _Float16* __restrict__ qkv_wt,
    const float* __restrict__ proj_w, _Float16* __restrict__ proj_wt,
    const unsigned char* __restrict__ mask, uint32_t* __restrict__ pm,
    const float* __restrict__ proj_b, float* __restrict__ bias_out) {
  __shared__ float t[64][65];
  const int bid = (int)blockIdx.x;
  const int tid = (int)threadIdx.x;
  if (bid < 8192) {
    // cvt_fp16: exactly 8192*256 = hsh_e/4 items
    const int i = bid * 256 + tid;
    float4 v = ((const float4*)hs)[i];
    h4 o = {(_Float16)v.x, (_Float16)v.y, (_Float16)v.z, (_Float16)v.w};
    *(h4*)&hs_h[4 * (size_t)i] = o;
  } else if (bid < 11264) {
    const int r = bid - 8192;  // 96 x 32
    transpose_body(qkv_w, qkv_wt, HID, 3 * HID, r % 96, r / 96, tid, t);
  } else if (bid < 12288) {
    const int r = bid - 11264;  // 32 x 32
    transpose_body(proj_w, proj_wt, HID, HID, r % 32, r / 32, tid, t);
  } else if (bid < 13312) {
    // pack_mask (R15 logic, shift always < 32)
    const int i = (bid - 12288) * 256 + tid;  // B*S*64 words
    const int w = i & 63, rr = (i >> 6) & (S_LEN - 1), b = i >> 17;
    const uint32_t* src =
        (const uint32_t*)(mask + ((size_t)b * S_LEN + rr) * S_LEN + w * 32);
    uint32_t bits = 0;
#pragma unroll
    for (int k = 0; k < 8; k++) {
      const uint32_t v = src[k];
      bits |= ((v & 0x000000FFu) ? 1u : 0u) << (4 * k);
      bits |= ((v & 0x0000FF00u) ? 1u : 0u) << (4 * k + 1);
      bits |= ((v & 0x00FF0000u) ? 1u : 0u) << (4 * k + 2);
      bits |= ((v & 0xFF000000u) ? 1u : 0u) << (4 * k + 3);
    }
    const int c0 = w * 32;
    uint32_t caus;
    if (c0 > rr) {
      caus = 0xFFFFFFFFu;
    } else if (rr - c0 >= 31) {
      caus = 0u;
    } else {
      caus = ~((2u << (rr - c0)) - 1u);
    }
    pm[i] = bits | caus;
  } else {
    const int i = (bid - 13312) * 256 + tid;
    if (i < HID) bias_out[i] = proj_b[i];
  }
}

// ---------------------------------------------------------------------------
// pack_kv (unchanged since R8).
// ---------------------------------------------------------------------------
__global__ __launch_bounds__(256) void pack_kv(
    const _Float16* __restrict__ mixed, _Float16* __restrict__ KP,
    _Float16* __restrict__ VP) {
  __shared__ _Float16 Tv[128 * 40];
  const int kt = blockIdx.x;
  const int z = blockIdx.y;  // b*NH + h
  const int kb = kt * 32;
  const int tid = threadIdx.x;
  const size_t RS = (size_t)BATCH * NHEAD * 384;
  const _Float16* base = mixed + (size_t)z * 384;

  {
    const int r = tid >> 3, d0 = (tid & 7) * 16;
    const _Float16* src = base + (size_t)(kb + r) * RS + 256 + d0;
    h8 v0 = *(const h8*)src;
    h8 v1 = *(const h8*)(src + 8);
#pragma unroll
    for (int e = 0; e < 8; e++) Tv[(d0 + e) * 40 + r] = v0[e];
#pragma unroll
    for (int e = 0; e < 8; e++) Tv[(d0 + 8 + e) * 40 + r] = v1[e];
  }
  __syncthreads();

  const size_t tb = ((size_t)z * 64 + kt) * 8 * 512;
#pragma unroll
  for (int c = 0; c < 2; c++) {
    const int idx = tid + 256 * c;  // 0..511
    const int i = idx >> 6, l = idx & 63;
    const int ln = l & 15, quad = l >> 4;
    {
      const int jn = i >> 2, kq = i & 3;
      h8 v = *(const h8*)(base + (size_t)(kb + 16 * jn + ln) * RS + 128 +
                          32 * kq + 8 * quad);
      *(h8*)&KP[tb + (size_t)i * 512 + l * 8] = v;
    }
    {
      h8 v = *(const h8*)&Tv[(16 * i + ln) * 40 + 8 * quad];
      *(h8*)&VP[tb + (size_t)i * 512 + l * 8] = v;
    }
  }
}

// ---------------------------------------------------------------------------
// flash_attn_v11 (R20, resubmitted R21) = v9 + COMPLEMENTARY-QT PAIRING.
// R19 counters: FETCH 26MB (not BW-bound), Occupancy 25% with 16 waves/CU
// resident => CU idle = qt imbalance (ntiles = 4qt+4 in [4,64]).
// Breadth-first dispatch gives CU c bids {c, c+256}; bid<256 maps exactly
// as v9 (qt = 15-qi in {8..15}); bid>=256 takes the COMPLEMENT (qt = qi in
// {0..7}) with the SAME z => every CU pair sums to exactly 68 tiles,
// same-z K/V locality preserved. Decode bijective over 512 blocks.
// ---------------------------------------------------------------------------
__global__ __launch_bounds__(512) void flash_attn_v11(
    const _Float16* __restrict__ mixed, const _Float16* __restrict__ KP,
    const _Float16* __restrict__ VP, const uint32_t* __restrict__ pmask,
    _Float16* __restrict__ ctx) {
  const int bid = (int)blockIdx.x;
  const int u = bid & 255, hi = bid >> 8;
  const int qi = u >> 5;                       // 0..7
  const int z = (u & 7) * 4 + ((u >> 3) & 3);  // XCD (u&7) owns 4 z-planes
  const int qt = hi ? qi : 15 - qi;  // pair {15-qi, qi}: 68 tiles/CU
  const int h = z & (NHEAD - 1), b = z >> 4;
  const int qb = qt * 128;
  const int tid = threadIdx.x;
  const int wave = tid >> 6, lane = tid & 63;
  const int ln = lane & 15, quad = lane >> 4;

  __shared__ _Float16 Kbuf[2][8 * 512];  // 2 x 8 KB, frag-chunk layout
  __shared__ _Float16 Vbuf[2][8 * 512];  // 2 x 8 KB
  __shared__ _Float16 St[8][16 * 40];    // 10.2 KB, per-wave P [16][32]

  const size_t RS = (size_t)BATCH * NHEAD * 384;
  const _Float16* base = mixed + (size_t)z * 384;
  const uint32_t* pmb = pmask + (size_t)b * S_LEN * 64;
  const float scale = 0.08838834764831845f;  // 1/sqrt(128)

  h8 qfrag[4];
  {
    const size_t row = (size_t)(qb + 16 * wave + ln);
#pragma unroll
    for (int kq = 0; kq < 4; kq++) {
      h8 v = *(const h8*)(base + row * RS + 32 * kq + 8 * quad);
#pragma unroll
      for (int j = 0; j < 8; j++) v[j] = (_Float16)((float)v[j] * scale);
      qfrag[kq] = v;
    }
  }

  f32x4 o[8];
#pragma unroll
  for (int nt = 0; nt < 8; nt++) o[nt] = (f32x4){0.f, 0.f, 0.f, 0.f};
  float lpart[4] = {0.f, 0.f, 0.f, 0.f};

  const int ntiles = 4 * qt + 4;  // K-tiles of 32, covering rows < qb+128

  const size_t zt = (size_t)z * 64;
#define STAGE(kt_, buf_)                                            \
  {                                                                 \
    const size_t tbk = (zt + (kt_)) * (8 * 512) + lane * 8;         \
    gload16(KP + tbk + wave * 512, &Kbuf[buf_][wave * 512]);        \
    gload16(VP + tbk + wave * 512, &Vbuf[buf_][wave * 512]);        \
  }

  STAGE(0, 0)  // prologue

  const uint32_t* pmr = pmb + (size_t)(qb + 16 * wave + 4 * quad) * 64;

  for (int kt = 0; kt < ntiles; kt++) {
    const int cur = kt & 1;
    __syncthreads();  // drains this tile's async loads; frees other buffer

    if (kt + 1 < ntiles) STAGE(kt + 1, cur ^ 1)  // lands during compute

    uint32_t mw[4];
#pragma unroll
    for (int r = 0; r < 4; r++) mw[r] = pmr[(size_t)r * 64 + kt];

    f32x4 sreg[2];
    sreg[0] = (f32x4){0.f, 0.f, 0.f, 0.f};
    sreg[1] = (f32x4){0.f, 0.f, 0.f, 0.f};
#pragma unroll
    for (int kq = 0; kq < 4; kq++) {
#pragma unroll
      for (int jn = 0; jn < 2; jn++) {
        h8 bk = *(const h8*)&Kbuf[cur][(jn * 4 + kq) * 512 + lane * 8];
        sreg[jn] = __builtin_amdgcn_mfma_f32_16x16x32_f16(qfrag[kq], bk,
                                                          sreg[jn], 0, 0, 0);
      }
    }

#pragma unroll
    for (int r = 0; r < 4; r++) {
      const uint32_t ms = mw[r] >> ln;  // bit 16*jn for col kb+16jn+ln
#pragma unroll
      for (int jn = 0; jn < 2; jn++) {
        const float sv =
            ((ms >> (16 * jn)) & 1u) ? -10000.0f : sreg[jn][r];
        const float p = __expf(sv);
        lpart[r] += p;
        St[wave][(4 * quad + r) * 40 + 16 * jn + ln] = (_Float16)p;
      }
    }
    __threadfence_block();

    {
      h8 ap = *(const h8*)&St[wave][ln * 40 + 8 * quad];
#pragma unroll
      for (int nt = 0; nt < 8; nt++) {
        h8 bv = *(const h8*)&Vbuf[cur][nt * 512 + lane * 8];
        o[nt] = __builtin_amdgcn_mfma_f32_16x16x32_f16(ap, bv, o[nt], 0, 0, 0);
      }
    }
  }
#undef STAGE

#pragma unroll
  for (int r = 0; r < 4; r++) {
    float l = lpart[r];
#pragma unroll
    for (int off = 8; off >= 1; off >>= 1) l += __shfl_xor(l, off, 16);
    const float inv_l = 1.0f / l;
    const size_t row_g = (size_t)(qb + 16 * wave + 4 * quad + r);
    _Float16* dst = ctx + (row_g * BATCH + b) * HID + h * DHEAD;
#pragma unroll
    for (int nt = 0; nt < 8; nt++)
      dst[16 * nt + ln] = (_Float16)(o[nt][r] * inv_l);
  }
}

extern "C" void kernel_launch(void* const* d_in, const int* in_sizes, int n_in,
                              void* d_out, int out_size, void* d_ws,
                              size_t ws_size, hipStream_t stream) {
  (void)in_sizes;
  (void)n_in;
  const float* hs = (const float*)d_in[0];
  const unsigned char* mask = (const unsigned char*)d_in[1];
  const float* qkv_w = (const float*)d_in[2];
  const float* qkv_b = (const float*)d_in[3];
  const float* proj_w = (const float*)d_in[4];
  const float* proj_b = (const float*)d_in[5];
  float* out = (float*)d_out;

  const size_t M = (size_t)S_LEN * BATCH;
  const size_t mixed_e = M * 3 * HID;            // 25.17M halves
  const size_t qkvwt_e = (size_t)3 * HID * HID;  // 12.58M (>= VP 8.39M)
  const size_t hsh_e = M * HID;                  // 8.39M (== KP 8.39M)
  const size_t projwt_e = (size_t)HID * HID;     // 4.19M
  const size_t ctx_e = M * HID;                  // 8.39M
  const size_t need =
      (mixed_e + qkvwt_e + hsh_e + projwt_e + ctx_e) * sizeof(_Float16);
  if (ws_size < need) return;  // 117.5 MB, proven available

  _Float16* mixed = (_Float16*)d_ws;
  _Float16* qkv_wt = mixed + mixed_e;   // aliased as VP after QKV GEMM
  _Float16* hs_h = qkv_wt + qkvwt_e;    // aliased as KP after QKV GEMM
  _Float16* proj_wt = hs_h + hsh_e;
  _Float16* ctx = proj_wt + projwt_e;
  _Float16* KP = hs_h;
  _Float16* VP = qkv_wt;
  // packed mask (1 MB) scratched into d_out[0..262144 words): dead until
  // proj GEMM, fully overwritten by it (proj writes out[0..M*HID)).
  // bias tail out[M*HID..M*HID+2048) written by prep, untouched by proj.
  uint32_t* pmask = (uint32_t*)out;

  // fused prep: cvt + 2 transposes + pack_mask + copy_bias (1 launch vs 5)
  prep<<<13320, 256, 0, stream>>>(hs, hs_h, qkv_w, qkv_wt, proj_w, proj_wt,
                                  mask, pmask, proj_b, out + M * HID);

  // QKV split into two EXACT-one-round dispatches (R19):
  //   cols [0,4096):    gemm_256v2, grid 16x16 = 256 blocks (997 TF/block)
  //   cols [4096,6144): gemm_128,   grid 8x32  = 256 blocks (775 TF/block)
  gemm_256v2<true, true><<<dim3(16, (int)(M / 256)), 512, 0, stream>>>(
      hs_h, qkv_wt, qkv_b, mixed, (int)M, 3 * HID, HID);
  gemm_128<true, true><<<dim3(8, (int)(M / 128)), 512, 0, stream>>>(
      hs_h, qkv_wt + (size_t)4096 * HID, qkv_b + 4096,
      (void*)(mixed + 4096), (int)M, 3 * HID, HID);

  pack_kv<<<dim3(S_LEN / 32, BATCH * NHEAD), 256, 0, stream>>>(mixed, KP, VP);

  // flash v11: 512 blocks; CU pair {c, c+256} = complementary qt, same z
  flash_attn_v11<<<512, 512, 0, stream>>>(mixed, KP, VP, pmask, ctx);

  // proj: gemm_128 grid (2048/256) x (4096/128) = 256 blocks = 1 full round
  gemm_128<false, false><<<dim3(HID / 256, M / 128), 512, 0, stream>>>(
      ctx, proj_wt, nullptr, out, (int)M, HID, HID);
}